// Round 5
// baseline (230.828 us; speedup 1.0000x reference)
//
#include <hip/hip_runtime.h>
#include <math.h>

#define NQ 8
#define DK 64
#define NB 8
#define NS 1024
#define RB 8            // rows per block in attn kernel

// ---------------- prep: values GEMM (blocks 0..2047) + density features (2048..2303) ----------------
// qd/kd layout: [tok][n*4 + {d0, d1, re, im}]  (32 floats per token)
// m[n] = dot4(qd[n], kd[n]) with the factor 2 folded into kd.z/.w
__global__ __launch_bounds__(256) void prep_kernel(
    const float* __restrict__ x,
    const float* __restrict__ theta_q,
    const float* __restrict__ theta_k,
    const float* __restrict__ Wv,
    const float* __restrict__ bv,
    float* __restrict__ qd, float* __restrict__ kd,
    float* __restrict__ values) {
    int bid = blockIdx.x;
    int tid = threadIdx.x;
    if (bid < 2048) {
        // values = x @ Wv^T + bv
        int t = bid * 4 + (tid >> 6);
        int d = tid & 63;
        const float4* xr = (const float4*)(x + (size_t)t * DK);
        const float4* wr = (const float4*)(Wv + (size_t)d * DK);
        float acc = bv[d];
#pragma unroll
        for (int j = 0; j < DK / 4; ++j) {
            float4 xv = xr[j], wv = wr[j];
            acc = fmaf(xv.x, wv.x, acc);
            acc = fmaf(xv.y, wv.y, acc);
            acc = fmaf(xv.z, wv.z, acc);
            acc = fmaf(xv.w, wv.w, acc);
        }
        values[(size_t)t * DK + d] = acc;
    } else {
        int gid = (bid - 2048) * 256 + tid;   // 0..65535
        int tok = gid >> 3;
        int n = gid & 7;
        float xin = x[(size_t)tok * DK + n];
        float ex = __expf(2.0f * xin);               // fast tanh
        float xn = 1.0f - 2.0f / (ex + 1.0f);
        float half = xn * 1.57079632679489662f;      // xn * pi/2
        float s, c;
        __sincosf(half, &s, &c);

        // Q side
        {
            float phi = theta_q[n * 3 + 0], th = theta_q[n * 3 + 1], om = theta_q[n * 3 + 2];
            float st, ct; __sincosf(0.5f * th, &st, &ct);
            float smpo, cmpo; __sincosf(0.5f * (phi + om), &smpo, &cmpo);
            float spmo, cpmo; __sincosf(0.5f * (phi - om), &spmo, &cpmo);
            float a = ct * c, b = st * s, cc = st * c, d = ct * s;
            float a0re =  cmpo * a - cpmo * b;
            float a0im = -smpo * a - spmo * b;
            float a1re =  cpmo * cc + cmpo * d;
            float a1im = -spmo * cc + smpo * d;
            float d0 = fmaf(a0re, a0re, a0im * a0im);
            float d1 = fmaf(a1re, a1re, a1im * a1im);
            float ur = fmaf(a1re, a0re, a1im * a0im);
            float ui = fmaf(a1im, a0re, -a1re * a0im);
            *(float4*)&qd[(size_t)tok * 32 + n * 4] = make_float4(d0, d1, ur, ui);
        }
        // K side (factor 2 on cross terms)
        {
            float phi = theta_k[n * 3 + 0], th = theta_k[n * 3 + 1], om = theta_k[n * 3 + 2];
            float st, ct; __sincosf(0.5f * th, &st, &ct);
            float smpo, cmpo; __sincosf(0.5f * (phi + om), &smpo, &cmpo);
            float spmo, cpmo; __sincosf(0.5f * (phi - om), &spmo, &cpmo);
            float a = ct * c, b = st * s, cc = st * c, d = ct * s;
            float a0re =  cmpo * a - cpmo * b;
            float a0im = -smpo * a - spmo * b;
            float a1re =  cpmo * cc + cmpo * d;
            float a1im = -spmo * cc + smpo * d;
            float d0 = fmaf(a0re, a0re, a0im * a0im);
            float d1 = fmaf(a1re, a1re, a1im * a1im);
            float ur = fmaf(a1re, a0re, a1im * a0im);
            float ui = fmaf(a1im, a0re, -a1re * a0im);
            *(float4*)&kd[(size_t)tok * 32 + n * 4] = make_float4(d0, d1, 2.f * ur, 2.f * ui);
        }
    }
}

// ---------------- attn: fused scores -> softmax -> attn + PV ----------------
// 1024 blocks x 256 threads. Block owns 8 rows of one batch.
__global__ __launch_bounds__(256, 4) void attn_kernel(
    const float* __restrict__ qd, const float* __restrict__ kd,
    const float* __restrict__ values,
    float* __restrict__ out, float* __restrict__ attn) {
    __shared__ float e_lds[RB][NS];       // 32 KB (reused as reduce scratch at the end)
    __shared__ float q_lds[RB][32];       // 1 KB
    __shared__ float sums_lds[4][RB];
    __shared__ float inv_lds[RB];

    int tid = threadIdx.x;
    int gr0 = blockIdx.x * RB;            // global row base (= b*NS + s0)
    int b = gr0 >> 10;
    int w = tid >> 6, lane = tid & 63;

    // stage Q density features for the block's 8 rows
    if (tid < RB * 8) {
        int r = tid >> 3, c = tid & 7;
        *(float4*)&q_lds[r][c * 4] = *(const float4*)&qd[((size_t)(gr0 + r)) * 32 + c * 4];
    }
    __syncthreads();

    const float* kfb = kd + (size_t)b * NS * 32;

    // ---- Phase 1: scores + exp, 2 tokens per q-read ----
    float sums[RB];
#pragma unroll
    for (int r = 0; r < RB; ++r) sums[r] = 0.f;

#pragma unroll
    for (int kk = 0; kk < 2; ++kk) {
        int t0 = kk * 512 + tid;
        int t1 = t0 + 256;
        const float4* kp0 = (const float4*)(kfb + ((size_t)t0 << 5));
        const float4* kp1 = (const float4*)(kfb + ((size_t)t1 << 5));
        float ka[32], kb[32];
#pragma unroll
        for (int c = 0; c < 8; ++c) {
            *(float4*)&ka[c * 4] = kp0[c];
            *(float4*)&kb[c * 4] = kp1[c];
        }
#pragma unroll
        for (int r = 0; r < RB; ++r) {
            float c0 = 1.f, c1 = 1.f;
#pragma unroll
            for (int n = 0; n < 8; ++n) {
                float4 q = *(const float4*)&q_lds[r][n * 4];   // wave-uniform broadcast
                float m0 = fmaf(q.x, ka[n*4+0], fmaf(q.y, ka[n*4+1], fmaf(q.z, ka[n*4+2], q.w * ka[n*4+3])));
                float m1 = fmaf(q.x, kb[n*4+0], fmaf(q.y, kb[n*4+1], fmaf(q.z, kb[n*4+2], q.w * kb[n*4+3])));
                c0 *= m0;
                c1 *= m1;
            }
            float e0 = __expf(fmaf(c0, 0.5f, 0.5f));  // score in [0.5,1] -> no max needed
            float e1 = __expf(fmaf(c1, 0.5f, 0.5f));
            e_lds[r][t0] = e0;
            e_lds[r][t1] = e1;
            sums[r] += e0 + e1;
        }
    }

    // wave-level row-sum reduce, then cross-wave combine
#pragma unroll
    for (int r = 0; r < RB; ++r) {
#pragma unroll
        for (int msk = 1; msk < 64; msk <<= 1) sums[r] += __shfl_xor(sums[r], msk, 64);
    }
    if (lane == 0) {
#pragma unroll
        for (int r = 0; r < RB; ++r) sums_lds[w][r] = sums[r];
    }
    __syncthreads();
    if (tid < RB)
        inv_lds[tid] = 1.f / (sums_lds[0][tid] + sums_lds[1][tid] + sums_lds[2][tid] + sums_lds[3][tid]);
    __syncthreads();

    float inv[RB];
#pragma unroll
    for (int r = 0; r < RB; ++r) inv[r] = inv_lds[r];

    // ---- Phase 2: write normalized attn (coalesced float4) ----
    float* ab = attn + (size_t)gr0 * NS;
#pragma unroll
    for (int r = 0; r < RB; ++r) {
        float4 e4 = *(const float4*)&e_lds[r][tid * 4];
        float iv = inv[r];
        *(float4*)&ab[(size_t)r * NS + tid * 4] =
            make_float4(e4.x * iv, e4.y * iv, e4.z * iv, e4.w * iv);
    }

    // ---- Phase 3: PV. thread (tg,dg): tokens tg*4 step 64, dims dg*4..+3 ----
    int tg = tid >> 4, dg = tid & 15;
    const float* vb = values + (size_t)b * NS * DK;
    float acc[RB][4];
#pragma unroll
    for (int r = 0; r < RB; ++r) { acc[r][0] = acc[r][1] = acc[r][2] = acc[r][3] = 0.f; }

#pragma unroll 4
    for (int jj = 0; jj < 16; ++jj) {
        int t = jj * 64 + tg * 4;
        const float* vp = vb + (size_t)t * DK + dg * 4;
        float4 v0 = *(const float4*)(vp);
        float4 v1 = *(const float4*)(vp + DK);
        float4 v2 = *(const float4*)(vp + 2 * DK);
        float4 v3 = *(const float4*)(vp + 3 * DK);
#pragma unroll
        for (int r = 0; r < RB; ++r) {
            float4 e4 = *(const float4*)&e_lds[r][t];
            acc[r][0] = fmaf(e4.x, v0.x, fmaf(e4.y, v1.x, fmaf(e4.z, v2.x, fmaf(e4.w, v3.x, acc[r][0]))));
            acc[r][1] = fmaf(e4.x, v0.y, fmaf(e4.y, v1.y, fmaf(e4.z, v2.y, fmaf(e4.w, v3.y, acc[r][1]))));
            acc[r][2] = fmaf(e4.x, v0.z, fmaf(e4.y, v1.z, fmaf(e4.z, v2.z, fmaf(e4.w, v3.z, acc[r][2]))));
            acc[r][3] = fmaf(e4.x, v0.w, fmaf(e4.y, v1.w, fmaf(e4.z, v2.w, fmaf(e4.w, v3.w, acc[r][3]))));
        }
    }

    // ---- out reduce: reuse e_lds as [16][8][64] scratch, 2 barriers total ----
    __syncthreads();                       // all PV reads of e_lds complete
    float* red = &e_lds[0][0];
#pragma unroll
    for (int r = 0; r < RB; ++r) {
        *(float4*)&red[tg * 512 + r * 64 + dg * 4] =
            make_float4(acc[r][0], acc[r][1], acc[r][2], acc[r][3]);
    }
    __syncthreads();
#pragma unroll
    for (int h = 0; h < 2; ++h) {
        int r = h * 4 + (tid >> 6);
        int d = tid & 63;
        float o = 0.f;
#pragma unroll
        for (int g = 0; g < 16; ++g) o += red[g * 512 + r * 64 + d];
        out[((size_t)(gr0 + r)) * DK + d] = o * inv_lds[r];
    }
}

extern "C" void kernel_launch(void* const* d_in, const int* in_sizes, int n_in,
                              void* d_out, int out_size, void* d_ws, size_t ws_size,
                              hipStream_t stream) {
    const float* x       = (const float*)d_in[0];
    const float* theta_q = (const float*)d_in[1];
    const float* theta_k = (const float*)d_in[2];
    const float* W_v     = (const float*)d_in[3];
    const float* b_v     = (const float*)d_in[4];

    float* out  = (float*)d_out;                        // [8,1024,64]
    float* attn = (float*)d_out + (size_t)NB * NS * DK; // [8,1024,1024]

    float* qd     = (float*)d_ws;                       // 8192*32 floats (1 MB)
    float* kd     = qd + (size_t)NB * NS * 32;          // 8192*32 floats (1 MB)
    float* values = kd + (size_t)NB * NS * 32;          // 8192*64 floats (2 MB)

    prep_kernel<<<2048 + NB * NS * NQ / 256, 256, 0, stream>>>(
        x, theta_q, theta_k, W_v, b_v, qd, kd, values);
    attn_kernel<<<NB * NS / RB, 256, 0, stream>>>(qd, kd, values, out, attn);
}

// Round 6
// 64.108 us; speedup vs baseline: 3.6006x; 3.6006x over previous
//
#include <hip/hip_runtime.h>
#include <math.h>

#define NQ 8
#define DK 64
#define NB 8
#define NS 1024
#define RB 8            // rows per block in attn kernel

// ---------------- prep: values GEMM (blocks 0..2047) + density features (2048..2303) ----------------
// qd/kd layout: [tok][n*4 + {d0, d1, re, im}]  (32 floats per token)
// m[n] = dot4(qd[n], kd[n]) with the factor 2 folded into kd.z/.w
__global__ __launch_bounds__(256) void prep_kernel(
    const float* __restrict__ x,
    const float* __restrict__ theta_q,
    const float* __restrict__ theta_k,
    const float* __restrict__ Wv,
    const float* __restrict__ bv,
    float* __restrict__ qd, float* __restrict__ kd,
    float* __restrict__ values) {
    int bid = blockIdx.x;
    int tid = threadIdx.x;
    if (bid < 2048) {
        // values = x @ Wv^T + bv
        int t = bid * 4 + (tid >> 6);
        int d = tid & 63;
        const float4* xr = (const float4*)(x + (size_t)t * DK);
        const float4* wr = (const float4*)(Wv + (size_t)d * DK);
        float acc = bv[d];
#pragma unroll
        for (int j = 0; j < DK / 4; ++j) {
            float4 xv = xr[j], wv = wr[j];
            acc = fmaf(xv.x, wv.x, acc);
            acc = fmaf(xv.y, wv.y, acc);
            acc = fmaf(xv.z, wv.z, acc);
            acc = fmaf(xv.w, wv.w, acc);
        }
        values[(size_t)t * DK + d] = acc;
    } else {
        int gid = (bid - 2048) * 256 + tid;   // 0..65535
        int tok = gid >> 3;
        int n = gid & 7;
        float xin = x[(size_t)tok * DK + n];
        float ex = __expf(2.0f * xin);               // fast tanh
        float xn = 1.0f - 2.0f / (ex + 1.0f);
        float half = xn * 1.57079632679489662f;      // xn * pi/2
        float s, c;
        __sincosf(half, &s, &c);

        // Q side
        {
            float phi = theta_q[n * 3 + 0], th = theta_q[n * 3 + 1], om = theta_q[n * 3 + 2];
            float st, ct; __sincosf(0.5f * th, &st, &ct);
            float smpo, cmpo; __sincosf(0.5f * (phi + om), &smpo, &cmpo);
            float spmo, cpmo; __sincosf(0.5f * (phi - om), &spmo, &cpmo);
            float a = ct * c, b = st * s, cc = st * c, d = ct * s;
            float a0re =  cmpo * a - cpmo * b;
            float a0im = -smpo * a - spmo * b;
            float a1re =  cpmo * cc + cmpo * d;
            float a1im = -spmo * cc + smpo * d;
            float d0 = fmaf(a0re, a0re, a0im * a0im);
            float d1 = fmaf(a1re, a1re, a1im * a1im);
            float ur = fmaf(a1re, a0re, a1im * a0im);
            float ui = fmaf(a1im, a0re, -a1re * a0im);
            *(float4*)&qd[(size_t)tok * 32 + n * 4] = make_float4(d0, d1, ur, ui);
        }
        // K side (factor 2 on cross terms)
        {
            float phi = theta_k[n * 3 + 0], th = theta_k[n * 3 + 1], om = theta_k[n * 3 + 2];
            float st, ct; __sincosf(0.5f * th, &st, &ct);
            float smpo, cmpo; __sincosf(0.5f * (phi + om), &smpo, &cmpo);
            float spmo, cpmo; __sincosf(0.5f * (phi - om), &spmo, &cpmo);
            float a = ct * c, b = st * s, cc = st * c, d = ct * s;
            float a0re =  cmpo * a - cpmo * b;
            float a0im = -smpo * a - spmo * b;
            float a1re =  cpmo * cc + cmpo * d;
            float a1im = -spmo * cc + smpo * d;
            float d0 = fmaf(a0re, a0re, a0im * a0im);
            float d1 = fmaf(a1re, a1re, a1im * a1im);
            float ur = fmaf(a1re, a0re, a1im * a0im);
            float ui = fmaf(a1im, a0re, -a1re * a0im);
            *(float4*)&kd[(size_t)tok * 32 + n * 4] = make_float4(d0, d1, 2.f * ur, 2.f * ui);
        }
    }
}

// ---------------- attn: fused scores -> softmax -> attn + PV ----------------
// 1024 blocks x 256 threads. Block owns 8 rows of one batch.
// Phase 1: lane=token (1 token/iter, 4 iters), computes 8 rows' e -> e_lds.
__global__ __launch_bounds__(256, 4) void attn_kernel(
    const float* __restrict__ qd, const float* __restrict__ kd,
    const float* __restrict__ values,
    float* __restrict__ out, float* __restrict__ attn) {
    __shared__ float e_lds[RB][NS];       // 32 KB (reused as reduce scratch at the end)
    __shared__ float q_lds[RB][32];       // 1 KB
    __shared__ float sums_lds[4][RB];
    __shared__ float inv_lds[RB];

    int tid = threadIdx.x;
    int gr0 = blockIdx.x * RB;            // global row base (= b*NS + s0)
    int b = gr0 >> 10;
    int w = tid >> 6, lane = tid & 63;

    // stage Q density features for the block's 8 rows
    if (tid < RB * 8) {
        int r = tid >> 3, c = tid & 7;
        *(float4*)&q_lds[r][c * 4] = *(const float4*)&qd[((size_t)(gr0 + r)) * 32 + c * 4];
    }
    __syncthreads();

    const float* kfb = kd + (size_t)b * NS * 32;

    // ---- Phase 1: scores + exp for all 1024 tokens x 8 rows ----
    float sums[RB];
#pragma unroll
    for (int r = 0; r < RB; ++r) sums[r] = 0.f;

#pragma unroll
    for (int kk = 0; kk < 4; ++kk) {
        int t = kk * 256 + tid;
        const float4* kp = (const float4*)(kfb + ((size_t)t << 5));
        float kq[32];
#pragma unroll
        for (int c = 0; c < 8; ++c) *(float4*)&kq[c * 4] = kp[c];
#pragma unroll
        for (int r = 0; r < RB; ++r) {
            float m[8];
#pragma unroll
            for (int n = 0; n < 8; ++n) {
                float4 q = *(const float4*)&q_lds[r][n * 4];   // wave-uniform broadcast
                m[n] = fmaf(q.x, kq[n*4+0],
                       fmaf(q.y, kq[n*4+1],
                       fmaf(q.z, kq[n*4+2], q.w * kq[n*4+3])));
            }
            float core = ((m[0]*m[1]) * (m[2]*m[3])) * ((m[4]*m[5]) * (m[6]*m[7]));
            float e = __expf(fmaf(core, 0.5f, 0.5f));  // score in [0.5,1] -> no max needed
            e_lds[r][t] = e;
            sums[r] += e;
        }
    }

    // wave-level row-sum reduce, then cross-wave combine
#pragma unroll
    for (int r = 0; r < RB; ++r) {
#pragma unroll
        for (int msk = 1; msk < 64; msk <<= 1) sums[r] += __shfl_xor(sums[r], msk, 64);
    }
    if (lane == 0) {
#pragma unroll
        for (int r = 0; r < RB; ++r) sums_lds[w][r] = sums[r];
    }
    __syncthreads();
    if (tid < RB)
        inv_lds[tid] = 1.f / (sums_lds[0][tid] + sums_lds[1][tid] + sums_lds[2][tid] + sums_lds[3][tid]);
    __syncthreads();

    float inv[RB];
#pragma unroll
    for (int r = 0; r < RB; ++r) inv[r] = inv_lds[r];

    // ---- Phase 2: write normalized attn (coalesced float4) ----
    float* ab = attn + (size_t)gr0 * NS;
#pragma unroll
    for (int r = 0; r < RB; ++r) {
        float4 e4 = *(const float4*)&e_lds[r][tid * 4];
        float iv = inv[r];
        *(float4*)&ab[(size_t)r * NS + tid * 4] =
            make_float4(e4.x * iv, e4.y * iv, e4.z * iv, e4.w * iv);
    }

    // ---- Phase 3: PV. thread (tg,dg): tokens tg*4 step 64, dims dg*4..+3 ----
    int tg = tid >> 4, dg = tid & 15;
    const float* vb = values + (size_t)b * NS * DK;
    float acc[RB][4];
#pragma unroll
    for (int r = 0; r < RB; ++r) { acc[r][0] = acc[r][1] = acc[r][2] = acc[r][3] = 0.f; }

    for (int jj = 0; jj < 16; ++jj) {
        int t = jj * 64 + tg * 4;
        const float* vp = vb + (size_t)t * DK + dg * 4;
        float4 v0 = *(const float4*)(vp);
        float4 v1 = *(const float4*)(vp + DK);
        float4 v2 = *(const float4*)(vp + 2 * DK);
        float4 v3 = *(const float4*)(vp + 3 * DK);
#pragma unroll
        for (int r = 0; r < RB; ++r) {
            float4 e4 = *(const float4*)&e_lds[r][t];
            acc[r][0] = fmaf(e4.x, v0.x, fmaf(e4.y, v1.x, fmaf(e4.z, v2.x, fmaf(e4.w, v3.x, acc[r][0]))));
            acc[r][1] = fmaf(e4.x, v0.y, fmaf(e4.y, v1.y, fmaf(e4.z, v2.y, fmaf(e4.w, v3.y, acc[r][1]))));
            acc[r][2] = fmaf(e4.x, v0.z, fmaf(e4.y, v1.z, fmaf(e4.z, v2.z, fmaf(e4.w, v3.z, acc[r][2]))));
            acc[r][3] = fmaf(e4.x, v0.w, fmaf(e4.y, v1.w, fmaf(e4.z, v2.w, fmaf(e4.w, v3.w, acc[r][3]))));
        }
    }

    // ---- out reduce: reuse e_lds as [16][8][64] scratch, 2 barriers total ----
    __syncthreads();                       // all PV reads of e_lds complete
    float* red = &e_lds[0][0];
#pragma unroll
    for (int r = 0; r < RB; ++r) {
        *(float4*)&red[tg * 512 + r * 64 + dg * 4] =
            make_float4(acc[r][0], acc[r][1], acc[r][2], acc[r][3]);
    }
    __syncthreads();
#pragma unroll
    for (int h = 0; h < 2; ++h) {
        int r = h * 4 + (tid >> 6);
        int d = tid & 63;
        float o = 0.f;
#pragma unroll
        for (int g = 0; g < 16; ++g) o += red[g * 512 + r * 64 + d];
        out[((size_t)(gr0 + r)) * DK + d] = o * inv_lds[r];
    }
}

extern "C" void kernel_launch(void* const* d_in, const int* in_sizes, int n_in,
                              void* d_out, int out_size, void* d_ws, size_t ws_size,
                              hipStream_t stream) {
    const float* x       = (const float*)d_in[0];
    const float* theta_q = (const float*)d_in[1];
    const float* theta_k = (const float*)d_in[2];
    const float* W_v     = (const float*)d_in[3];
    const float* b_v     = (const float*)d_in[4];

    float* out  = (float*)d_out;                        // [8,1024,64]
    float* attn = (float*)d_out + (size_t)NB * NS * DK; // [8,1024,1024]

    float* qd     = (float*)d_ws;                       // 8192*32 floats (1 MB)
    float* kd     = qd + (size_t)NB * NS * 32;          // 8192*32 floats (1 MB)
    float* values = kd + (size_t)NB * NS * 32;          // 8192*64 floats (2 MB)

    prep_kernel<<<2048 + NB * NS * NQ / 256, 256, 0, stream>>>(
        x, theta_q, theta_k, W_v, b_v, qd, kd, values);
    attn_kernel<<<NB * NS / RB, 256, 0, stream>>>(qd, kd, values, out, attn);
}